// Round 7
// baseline (84.245 us; speedup 1.0000x reference)
//
#include <hip/hip_runtime.h>

// CRF-RNN collapsed: out[t,i] = sum_j M[i,j] * orig[t,j],
//   orig[t,j] = sum_m inputs[t,j,m]*W_feat[m]
//   M = (I + B + B^2 + B^3) * diag(1/denom) + B^4
//   B[i,j] = 2*Kmat[i,j]/denom[i], Kmat[i,j] = sum_k kernels[i,j,k]*W_lin[k]
//   denom[i] = sum(W_feat) + 2*sum_j Kmat[i,j]

#define NREG 256   // N
#define KG   16    // gaussian kernels
#define MF   8     // features
#define BT   32    // t-rows per block in main kernel (256 threads)
#define PJ   8     // j-rows per MT panel staged in LDS
#define NPAN (NREG / PJ)   // 32

// async global->LDS, 16 B per lane. LDS dest is wave-uniform base;
// HW writes lane i at base + 16*i. Global src is per-lane.
__device__ __forceinline__ void async_copy16(const float* g, float* l) {
    __builtin_amdgcn_global_load_lds(
        (const __attribute__((address_space(1))) void*)g,
        (__attribute__((address_space(3))) void*)l,
        16, 0, 0);
}

// ---------------- K1: Kmat row, denom, B, Einv ----------------
__global__ __launch_bounds__(256) void k_prep(const float* __restrict__ kern,
                                              const float* __restrict__ Wlin,
                                              const float* __restrict__ Wfeat,
                                              float* __restrict__ B,
                                              float* __restrict__ Einv) {
    const int i = blockIdx.x, j = threadIdx.x;
    const float* kp = kern + ((size_t)i * NREG + j) * KG;
    float4 w0 = *(const float4*)(Wlin + 0);
    float4 w1 = *(const float4*)(Wlin + 4);
    float4 w2 = *(const float4*)(Wlin + 8);
    float4 w3 = *(const float4*)(Wlin + 12);
    float4 v0 = *(const float4*)(kp + 0);
    float4 v1 = *(const float4*)(kp + 4);
    float4 v2 = *(const float4*)(kp + 8);
    float4 v3 = *(const float4*)(kp + 12);
    float km = v0.x*w0.x + v0.y*w0.y + v0.z*w0.z + v0.w*w0.w
             + v1.x*w1.x + v1.y*w1.y + v1.z*w1.z + v1.w*w1.w
             + v2.x*w2.x + v2.y*w2.y + v2.z*w2.z + v2.w*w2.w
             + v3.x*w3.x + v3.y*w3.y + v3.z*w3.z + v3.w*w3.w;

    __shared__ float red[256];
    red[j] = km;
    __syncthreads();
    for (int s = 128; s > 0; s >>= 1) {
        if (j < s) red[j] += red[j + s];
        __syncthreads();
    }
    __shared__ float sden;
    if (j == 0) {
        float fw = 0.f;
#pragma unroll
        for (int m = 0; m < MF; ++m) fw += Wfeat[m];
        float den = fw + 2.f * red[0];
        sden = den;
        Einv[i] = 1.f / den;
    }
    __syncthreads();
    B[(size_t)i * NREG + j] = 2.f * km / sden;
}

// ---------------- generic 256x256 matmul body (Out = A*Bm) ----------------
__device__ __forceinline__ void mm_body(const float* __restrict__ A,
                                        const float* __restrict__ Bm,
                                        float* __restrict__ Out,
                                        int i0, int tid) {
    __shared__ float Ar[4][NREG];
#pragma unroll
    for (int r = 0; r < 4; ++r) Ar[r][tid] = A[(size_t)(i0 + r) * NREG + tid];
    __syncthreads();
    float acc0 = 0.f, acc1 = 0.f, acc2 = 0.f, acc3 = 0.f;
    for (int l = 0; l < NREG; l += 4) {
        float b0 = Bm[(size_t)(l + 0) * NREG + tid];
        float b1 = Bm[(size_t)(l + 1) * NREG + tid];
        float b2 = Bm[(size_t)(l + 2) * NREG + tid];
        float b3 = Bm[(size_t)(l + 3) * NREG + tid];
        float4 a0 = *(const float4*)&Ar[0][l];
        float4 a1 = *(const float4*)&Ar[1][l];
        float4 a2 = *(const float4*)&Ar[2][l];
        float4 a3 = *(const float4*)&Ar[3][l];
        acc0 += a0.x*b0 + a0.y*b1 + a0.z*b2 + a0.w*b3;
        acc1 += a1.x*b0 + a1.y*b1 + a1.z*b2 + a1.w*b3;
        acc2 += a2.x*b0 + a2.y*b1 + a2.z*b2 + a2.w*b3;
        acc3 += a3.x*b0 + a3.y*b1 + a3.z*b2 + a3.w*b3;
    }
    Out[(size_t)(i0 + 0) * NREG + tid] = acc0;
    Out[(size_t)(i0 + 1) * NREG + tid] = acc1;
    Out[(size_t)(i0 + 2) * NREG + tid] = acc2;
    Out[(size_t)(i0 + 3) * NREG + tid] = acc3;
}

// K2: C = B*B   (grid 64)
__global__ __launch_bounds__(256) void k_mm(const float* __restrict__ A,
                                            const float* __restrict__ Bm,
                                            float* __restrict__ Out) {
    mm_body(A, Bm, Out, blockIdx.x * 4, threadIdx.x);
}

// K3: G1 = B*C (blocks 0..63), G2 = C*C (blocks 64..127)
__global__ __launch_bounds__(256) void k_mm2(const float* __restrict__ B,
                                             const float* __restrict__ C,
                                             float* __restrict__ G1,
                                             float* __restrict__ G2) {
    const bool second = blockIdx.x >= 64;
    const float* A = second ? C : B;
    float* Out = second ? G2 : G1;
    mm_body(A, C, Out, (blockIdx.x & 63) * 4, threadIdx.x);
}

// K4: MT[j][i] = ((i==j) + B + C + G1)[i][j] * Einv[j] + G2[i][j]
__global__ __launch_bounds__(256) void k_comb(const float* __restrict__ B,
                                              const float* __restrict__ C,
                                              const float* __restrict__ G1,
                                              const float* __restrict__ G2,
                                              const float* __restrict__ Einv,
                                              float* __restrict__ MT) {
    const int i = blockIdx.x, j = threadIdx.x;
    const size_t idx = (size_t)i * NREG + j;
    float v = ((i == j) ? 1.f : 0.f) + B[idx] + C[idx] + G1[idx];
    v = v * Einv[j] + G2[idx];
    MT[(size_t)j * NREG + i] = v;
}

// ---------------- K5: fused feature-reduce + (T x N) * MT ----------------
// ALL global reads go through global_load_lds (no VGPR-mediated streams).
// Stage 1: per-wave 2-deep LDS ring of 4 KB raw-input chunks, counted
//   vmcnt(4) waits, no barriers (orig rows are wave-private).
//   RACE FIX (r6->r7): ds_read completion (lgkmcnt) and global_load_lds
//   LDS-writes (vmcnt data-return) are NOT cross-ordered. The refill of a
//   ring slot must only be ISSUED after the slot's reads have RETURNED:
//   s_waitcnt lgkmcnt(0) before the refill issue.
// Stage 2: MT j-panels (PJ=8 rows) double-buffered via async, barrier/panel.
// LDS: orig 32K + ring 32K + panels 16K = 80 KB -> 2 blocks/CU.
__global__ __launch_bounds__(256, 2) void k_main(const float* __restrict__ in,
                                                 const float* __restrict__ Wfeat,
                                                 const float* __restrict__ MT,
                                                 float* __restrict__ out) {
    __shared__ float orig[BT][NREG];        // 32 KB
    __shared__ float raws[4][2][1024];      // 32 KB: [wave][ring buf][4KB chunk]
    __shared__ float mtp[2][PJ][NREG];      // 16 KB
    const int tid  = threadIdx.x;
    const int lane = tid & 63;
    const int wid  = tid >> 6;              // 0..3
    const size_t t0 = (size_t)blockIdx.x * BT;
    const int tg = wid * 8;                 // wave's 8 t-rows

    // Wfeat into VGPRs, forced live BEFORE any async issue so the compiler's
    // vmcnt bookkeeping for these loads can't insert a drain mid-pipeline.
    float4 wa = *(const float4*)(Wfeat);
    float4 wb = *(const float4*)(Wfeat + 4);
    asm volatile("" :: "v"(wa.x), "v"(wa.y), "v"(wa.z), "v"(wa.w),
                       "v"(wb.x), "v"(wb.y), "v"(wb.z), "v"(wb.w));

    // ---- stage 1: wave-private async ring. chunk c (0..15): row r=c>>1,
    // half h=c&1; 4 KB = 4 async instrs of 1 KB (64 lanes x 16 B).
    const float* wbase = in + (t0 + tg) * (NREG * MF);
#pragma unroll
    for (int c = 0; c < 2; ++c) {   // prologue: fill both ring slots
        const float* src = wbase + (size_t)(c >> 1) * 2048 + (size_t)(c & 1) * 1024;
#pragma unroll
        for (int q = 0; q < 4; ++q)
            async_copy16(src + q * 256 + lane * 4, &raws[wid][c & 1][q * 256]);
    }
#pragma unroll
    for (int c = 0; c < 16; ++c) {
        if (c < 15) { asm volatile("s_waitcnt vmcnt(4)" ::: "memory"); }
        else       { asm volatile("s_waitcnt vmcnt(0)" ::: "memory"); }
        __builtin_amdgcn_sched_barrier(0);
        // reduce: lane handles cells 2*lane, 2*lane+1 of this 1024-float chunk
        const float* rb = &raws[wid][c & 1][lane * 16];
        float4 a0 = *(const float4*)(rb + 0);
        float4 a1 = *(const float4*)(rb + 4);
        float4 b0 = *(const float4*)(rb + 8);
        float4 b1 = *(const float4*)(rb + 12);
        // fence: reads of this slot must have RETURNED before the refill of
        // the same slot is issued (ds_read vs VMEM->LDS write are unordered)
        asm volatile("s_waitcnt lgkmcnt(0)" ::: "memory");
        __builtin_amdgcn_sched_barrier(0);
        if (c + 2 < 16) {   // refill freed slot, now provably safe
            const int cn = c + 2;
            const float* src = wbase + (size_t)(cn >> 1) * 2048 + (size_t)(cn & 1) * 1024;
#pragma unroll
            for (int q = 0; q < 4; ++q)
                async_copy16(src + q * 256 + lane * 4, &raws[wid][cn & 1][q * 256]);
        }
        float o0 = a0.x*wa.x + a0.y*wa.y + a0.z*wa.z + a0.w*wa.w
                 + a1.x*wb.x + a1.y*wb.y + a1.z*wb.z + a1.w*wb.w;
        float o1 = b0.x*wa.x + b0.y*wa.y + b0.z*wa.z + b0.w*wa.w
                 + b1.x*wb.x + b1.y*wb.y + b1.z*wb.z + b1.w*wb.w;
        const int r = c >> 1, h = c & 1;
        *(float2*)&orig[tg + r][h * 128 + lane * 2] = make_float2(o0, o1);
    }

    // prefetch MT panel 0: 8 rows; wave w stages rows w and w+4 (1 KB each)
#pragma unroll
    for (int l = 0; l < PJ / 4; ++l) {
        const int r = l * 4 + wid;
        async_copy16(MT + (size_t)r * NREG + lane * 4, &mtp[0][r][0]);
    }
    __syncthreads();   // drains vmcnt -> panel 0 resident; orig all written

    // ---- stage 2: out[t, i] = sum_j orig[t][j] * MT[j][i], panel-pipelined
    const int i4 = lane;          // column block of 4 i's
    float4 acc[8];
#pragma unroll
    for (int t = 0; t < 8; ++t) acc[t] = make_float4(0.f, 0.f, 0.f, 0.f);

    int buf = 0;
    for (int p = 0; p < NPAN; ++p) {
        if (p + 1 < NPAN) {       // issue next panel's async loads
            const int j0n = (p + 1) * PJ;
#pragma unroll
            for (int l = 0; l < PJ / 4; ++l) {
                const int r = l * 4 + wid;
                async_copy16(MT + (size_t)(j0n + r) * NREG + lane * 4,
                             &mtp[buf ^ 1][r][0]);
            }
        }
        const int jbase = p * PJ;
#pragma unroll
        for (int jj = 0; jj < PJ; jj += 4) {
            float4 m0 = *(const float4*)&mtp[buf][jj + 0][i4 * 4];
            float4 m1 = *(const float4*)&mtp[buf][jj + 1][i4 * 4];
            float4 m2 = *(const float4*)&mtp[buf][jj + 2][i4 * 4];
            float4 m3 = *(const float4*)&mtp[buf][jj + 3][i4 * 4];
#pragma unroll
            for (int t = 0; t < 8; ++t) {
                float4 ov = *(const float4*)&orig[tg + t][jbase + jj];  // broadcast
                acc[t].x += ov.x*m0.x + ov.y*m1.x + ov.z*m2.x + ov.w*m3.x;
                acc[t].y += ov.x*m0.y + ov.y*m1.y + ov.z*m2.y + ov.w*m3.y;
                acc[t].z += ov.x*m0.z + ov.y*m1.z + ov.z*m2.z + ov.w*m3.z;
                acc[t].w += ov.x*m0.w + ov.y*m1.w + ov.z*m2.w + ov.w*m3.w;
            }
        }
        __syncthreads();          // drain: next panel resident, buf free
        buf ^= 1;
    }

#pragma unroll
    for (int t = 0; t < 8; ++t) {
        ((float4*)(out + (t0 + tg + t) * NREG))[i4] = acc[t];
    }
}

extern "C" void kernel_launch(void* const* d_in, const int* in_sizes, int n_in,
                              void* d_out, int out_size, void* d_ws, size_t ws_size,
                              hipStream_t stream) {
    const float* inputs  = (const float*)d_in[0];  // (16384, 256, 8)
    const float* kernels = (const float*)d_in[1];  // (256, 256, 16)
    const float* Wfeat   = (const float*)d_in[2];  // (1, 8)
    const float* Wlin    = (const float*)d_in[3];  // (1, 16)
    float* out = (float*)d_out;                    // (16384, 256)

    float* ws   = (float*)d_ws;                    // needs ~1.32 MB
    float* B    = ws;                              // 65536
    float* C    = B  + NREG * NREG;                // 65536  (B^2)
    float* G1   = C  + NREG * NREG;                // 65536  (B^3)
    float* G2   = G1 + NREG * NREG;                // 65536  (B^4)
    float* Einv = G2 + NREG * NREG;                // 256
    float* MT   = Einv + NREG;                     // 65536  (M transposed)

    k_prep<<<256, 256, 0, stream>>>(kernels, Wlin, Wfeat, B, Einv);
    k_mm  <<<64,  256, 0, stream>>>(B, B, C);
    k_mm2 <<<128, 256, 0, stream>>>(B, C, G1, G2);
    k_comb<<<256, 256, 0, stream>>>(B, C, G1, G2, Einv, MT);
    k_main<<<16384 / BT, 256, 0, stream>>>(inputs, Wfeat, MT, out);
}

// Round 8
// 62.510 us; speedup vs baseline: 1.3477x; 1.3477x over previous
//
#include <hip/hip_runtime.h>

// CRF-RNN collapsed: out[t,i] = sum_j M[i,j] * orig[t,j],
//   orig[t,j] = sum_m inputs[t,j,m]*W_feat[m]
//   M = (I + B + B^2 + B^3) * diag(1/denom) + B^4
// Stage-2 computed with split-bf16 MFMA: x = hi + lo (bf16 each),
//   A*B ~= Ah*Bh + Ah*Bl + Al*Bh  (Al*Bl ~ 2^-32, dropped)

#define NREG 256   // N
#define KG   16    // gaussian kernels
#define MF   8     // features

typedef unsigned short u16;
typedef __attribute__((ext_vector_type(8))) short short8;   // 8 bf16 = 4 VGPR
typedef __attribute__((ext_vector_type(4))) float f32x4;

// async global->LDS, 16 B per lane: HW writes lane i at ldsbase + 16*i.
__device__ __forceinline__ void async_copy16(const void* g, void* l) {
    __builtin_amdgcn_global_load_lds(
        (const __attribute__((address_space(1))) void*)g,
        (__attribute__((address_space(3))) void*)l,
        16, 0, 0);
}

// round-to-nearest-even float -> bf16 bits
__device__ __forceinline__ u16 bf16_rne(float x) {
    unsigned u = __float_as_uint(x);
    return (u16)((u + 0x7FFFu + ((u >> 16) & 1u)) >> 16);
}
__device__ __forceinline__ float bf16_to_f(u16 h) {
    return __uint_as_float(((unsigned)h) << 16);
}

// ---------------- K1: Kmat row, denom, B, Einv ----------------
__global__ __launch_bounds__(256) void k_prep(const float* __restrict__ kern,
                                              const float* __restrict__ Wlin,
                                              const float* __restrict__ Wfeat,
                                              float* __restrict__ B,
                                              float* __restrict__ Einv) {
    const int i = blockIdx.x, j = threadIdx.x;
    const float* kp = kern + ((size_t)i * NREG + j) * KG;
    float4 w0 = *(const float4*)(Wlin + 0);
    float4 w1 = *(const float4*)(Wlin + 4);
    float4 w2 = *(const float4*)(Wlin + 8);
    float4 w3 = *(const float4*)(Wlin + 12);
    float4 v0 = *(const float4*)(kp + 0);
    float4 v1 = *(const float4*)(kp + 4);
    float4 v2 = *(const float4*)(kp + 8);
    float4 v3 = *(const float4*)(kp + 12);
    float km = v0.x*w0.x + v0.y*w0.y + v0.z*w0.z + v0.w*w0.w
             + v1.x*w1.x + v1.y*w1.y + v1.z*w1.z + v1.w*w1.w
             + v2.x*w2.x + v2.y*w2.y + v2.z*w2.z + v2.w*w2.w
             + v3.x*w3.x + v3.y*w3.y + v3.z*w3.z + v3.w*w3.w;

    __shared__ float red[256];
    red[j] = km;
    __syncthreads();
    for (int s = 128; s > 0; s >>= 1) {
        if (j < s) red[j] += red[j + s];
        __syncthreads();
    }
    __shared__ float sden;
    if (j == 0) {
        float fw = 0.f;
#pragma unroll
        for (int m = 0; m < MF; ++m) fw += Wfeat[m];
        float den = fw + 2.f * red[0];
        sden = den;
        Einv[i] = 1.f / den;
    }
    __syncthreads();
    B[(size_t)i * NREG + j] = 2.f * km / sden;
}

// ---------------- generic 256x256 matmul body (Out = A*Bm) ----------------
__device__ __forceinline__ void mm_body(const float* __restrict__ A,
                                        const float* __restrict__ Bm,
                                        float* __restrict__ Out,
                                        int i0, int tid) {
    __shared__ float Ar[4][NREG];
#pragma unroll
    for (int r = 0; r < 4; ++r) Ar[r][tid] = A[(size_t)(i0 + r) * NREG + tid];
    __syncthreads();
    float acc0 = 0.f, acc1 = 0.f, acc2 = 0.f, acc3 = 0.f;
    for (int l = 0; l < NREG; l += 4) {
        float b0 = Bm[(size_t)(l + 0) * NREG + tid];
        float b1 = Bm[(size_t)(l + 1) * NREG + tid];
        float b2 = Bm[(size_t)(l + 2) * NREG + tid];
        float b3 = Bm[(size_t)(l + 3) * NREG + tid];
        float4 a0 = *(const float4*)&Ar[0][l];
        float4 a1 = *(const float4*)&Ar[1][l];
        float4 a2 = *(const float4*)&Ar[2][l];
        float4 a3 = *(const float4*)&Ar[3][l];
        acc0 += a0.x*b0 + a0.y*b1 + a0.z*b2 + a0.w*b3;
        acc1 += a1.x*b0 + a1.y*b1 + a1.z*b2 + a1.w*b3;
        acc2 += a2.x*b0 + a2.y*b1 + a2.z*b2 + a2.w*b3;
        acc3 += a3.x*b0 + a3.y*b1 + a3.z*b2 + a3.w*b3;
    }
    Out[(size_t)(i0 + 0) * NREG + tid] = acc0;
    Out[(size_t)(i0 + 1) * NREG + tid] = acc1;
    Out[(size_t)(i0 + 2) * NREG + tid] = acc2;
    Out[(size_t)(i0 + 3) * NREG + tid] = acc3;
}

__global__ __launch_bounds__(256) void k_mm(const float* __restrict__ A,
                                            const float* __restrict__ Bm,
                                            float* __restrict__ Out) {
    mm_body(A, Bm, Out, blockIdx.x * 4, threadIdx.x);
}

__global__ __launch_bounds__(256) void k_mm2(const float* __restrict__ B,
                                             const float* __restrict__ C,
                                             float* __restrict__ G1,
                                             float* __restrict__ G2) {
    const bool second = blockIdx.x >= 64;
    const float* A = second ? C : B;
    float* Out = second ? G2 : G1;
    mm_body(A, C, Out, (blockIdx.x & 63) * 4, threadIdx.x);
}

// K4: M[i][j] (fp32) -> split bf16 Mh/Ml, row-major [i][j]
__global__ __launch_bounds__(256) void k_comb(const float* __restrict__ B,
                                              const float* __restrict__ C,
                                              const float* __restrict__ G1,
                                              const float* __restrict__ G2,
                                              const float* __restrict__ Einv,
                                              u16* __restrict__ Mh,
                                              u16* __restrict__ Ml) {
    const int i = blockIdx.x, j = threadIdx.x;
    const size_t idx = (size_t)i * NREG + j;
    float v = ((i == j) ? 1.f : 0.f) + B[idx] + C[idx] + G1[idx];
    v = v * Einv[j] + G2[idx];
    u16 h = bf16_rne(v);
    float lo = v - bf16_to_f(h);
    Mh[idx] = h;
    Ml[idx] = bf16_rne(lo);
}

// ---------------- K5: fused feature-reduce + MFMA GEMM ----------------
// Block = 256 thr (4 waves), 64 t-rows; grid 256 (1 block/CU).
// Stage 1: async ring (r7-verified pattern) streams in -> orig -> split bf16
//          into XOR-swizzled LDS Ah/Al [64 t][256 j].
// Stage 2: 4 K-panels of 64 j: stage Mh/Ml panel [256 i][64 j] (swizzled via
//          pre-swizzled gll source), then 16x16x32 bf16 MFMA, 3 products.
// XOR swizzle: 16B-chunk index ^= (row & 7)  (kills 16-way row-stride conflicts)
__global__ __launch_bounds__(256, 1) void k_main(const float* __restrict__ in,
                                                 const float* __restrict__ Wfeat,
                                                 const u16* __restrict__ Mh,
                                                 const u16* __restrict__ Ml,
                                                 float* __restrict__ out) {
    __shared__ __align__(16) u16 Ah[64 * 256];     // 32 KB
    __shared__ __align__(16) u16 Al[64 * 256];     // 32 KB
    __shared__ __align__(16) u16 Bh[256 * 64];     // 32 KB
    __shared__ __align__(16) u16 Bl[256 * 64];     // 32 KB
    __shared__ __align__(16) float raws[4][2][512];// 16 KB ring
    const int tid = threadIdx.x, lane = tid & 63, wid = tid >> 6;
    const size_t t0 = (size_t)blockIdx.x * 64;

    // Wfeat live before any async issue (keeps its waitcnt out of the ring)
    float4 wa = *(const float4*)(Wfeat);
    float4 wb = *(const float4*)(Wfeat + 4);
    asm volatile("" :: "v"(wa.x), "v"(wa.y), "v"(wa.z), "v"(wa.w),
                       "v"(wb.x), "v"(wb.y), "v"(wb.z), "v"(wb.w));

    // ---- stage 1: wave streams its 16 t-rows in 64 chunks of 512 floats.
    // chunk c: t_local=c>>2, quarter q=c&3; 2 async instrs of 1 KB each.
    const float* wbase = in + (t0 + wid * 16) * (NREG * MF);
#pragma unroll
    for (int c = 0; c < 2; ++c) {
        const float* src = wbase + (size_t)(c >> 2) * 2048 + (size_t)(c & 3) * 512;
        async_copy16(src + lane * 4,       &raws[wid][c & 1][0]);
        async_copy16(src + 256 + lane * 4, &raws[wid][c & 1][256]);
    }
#pragma unroll 4
    for (int c = 0; c < 64; ++c) {
        if (c < 63) { asm volatile("s_waitcnt vmcnt(2)" ::: "memory"); }
        else        { asm volatile("s_waitcnt vmcnt(0)" ::: "memory"); }
        __builtin_amdgcn_sched_barrier(0);
        const float* rb = &raws[wid][c & 1][lane * 8];
        float4 a0 = *(const float4*)(rb + 0);
        float4 a1 = *(const float4*)(rb + 4);
        // reads must RETURN before refilling this slot (ds vs VMEM->LDS unordered)
        asm volatile("s_waitcnt lgkmcnt(0)" ::: "memory");
        __builtin_amdgcn_sched_barrier(0);
        if (c + 2 < 64) {
            const int cn = c + 2;
            const float* src = wbase + (size_t)(cn >> 2) * 2048 + (size_t)(cn & 3) * 512;
            async_copy16(src + lane * 4,       &raws[wid][cn & 1][0]);
            async_copy16(src + 256 + lane * 4, &raws[wid][cn & 1][256]);
        }
        float o = a0.x*wa.x + a0.y*wa.y + a0.z*wa.z + a0.w*wa.w
                + a1.x*wb.x + a1.y*wb.y + a1.z*wb.z + a1.w*wb.w;
        u16 h = bf16_rne(o);
        u16 l2 = bf16_rne(o - bf16_to_f(h));
        const int tl = c >> 2, q = c & 3;
        const int t = wid * 16 + tl;
        const int chunk = q * 8 + (lane >> 3);
        const int swz = chunk ^ (tl & 7);          // t&7 == tl&7 (wid*16 % 8 == 0)
        const int idx = t * 256 + swz * 8 + (lane & 7);
        Ah[idx] = h;
        Al[idx] = l2;
    }
    __syncthreads();   // orig split resident; vmcnt drained

    // ---- stage 2: K-panel MFMA loop
    f32x4 acc[16];
#pragma unroll
    for (int n = 0; n < 16; ++n) acc[n] = (f32x4){0.f, 0.f, 0.f, 0.f};

    for (int p = 0; p < 4; ++p) {
        if (p) __syncthreads();      // previous panel fully consumed
        // stage B panel: 64 gll instrs total (16/wave), 1 KB each (8 i-rows).
        // dest linear; source pre-swizzled: chunk' = chunk ^ (row&7)
#pragma unroll
        for (int s = 0; s < 16; ++s) {
            const int g = s * 4 + wid;          // 0..63
            const int i0 = (g & 31) * 8;
            const u16* sg = (g >> 5) ? Ml : Mh;
            u16* dg = (g >> 5) ? Bl : Bh;
            const int irow = i0 + (lane >> 3);
            const int ch = (lane & 7) ^ (lane >> 3);
            async_copy16(sg + (size_t)irow * NREG + p * 64 + ch * 8,
                         dg + i0 * 64);
        }
        __syncthreads();             // panel resident (compiler drains vmcnt)

#pragma unroll
        for (int kst = 0; kst < 2; ++kst) {
            const int trow = wid * 16 + (lane & 15);
            const int achunk = (8 * p + 4 * kst + (lane >> 4)) ^ (lane & 7);
            short8 a_h = *(const short8*)(Ah + trow * 256 + achunk * 8);
            short8 a_l = *(const short8*)(Al + trow * 256 + achunk * 8);
#pragma unroll
            for (int n = 0; n < 16; ++n) {
                const int irow = n * 16 + (lane & 15);
                const int bchunk = (4 * kst + (lane >> 4)) ^ (lane & 7);
                short8 b_h = *(const short8*)(Bh + irow * 64 + bchunk * 8);
                short8 b_l = *(const short8*)(Bl + irow * 64 + bchunk * 8);
                acc[n] = __builtin_amdgcn_mfma_f32_16x16x32_bf16(a_h, b_h, acc[n], 0, 0, 0);
                acc[n] = __builtin_amdgcn_mfma_f32_16x16x32_bf16(a_h, b_l, acc[n], 0, 0, 0);
                acc[n] = __builtin_amdgcn_mfma_f32_16x16x32_bf16(a_l, b_h, acc[n], 0, 0, 0);
            }
        }
    }

    // ---- epilogue: D col = lane&15 (i), row = (lane>>4)*4 + reg (t)
    const size_t tbase = t0 + wid * 16 + (lane >> 4) * 4;
#pragma unroll
    for (int n = 0; n < 16; ++n) {
#pragma unroll
        for (int r = 0; r < 4; ++r) {
            out[(tbase + r) * NREG + n * 16 + (lane & 15)] = acc[n][r];
        }
    }
}

extern "C" void kernel_launch(void* const* d_in, const int* in_sizes, int n_in,
                              void* d_out, int out_size, void* d_ws, size_t ws_size,
                              hipStream_t stream) {
    const float* inputs  = (const float*)d_in[0];  // (16384, 256, 8)
    const float* kernels = (const float*)d_in[1];  // (256, 256, 16)
    const float* Wfeat   = (const float*)d_in[2];  // (1, 8)
    const float* Wlin    = (const float*)d_in[3];  // (1, 16)
    float* out = (float*)d_out;                    // (16384, 256)

    float* ws   = (float*)d_ws;                    // ~1.26 MB
    float* B    = ws;                              // 65536 f
    float* C    = B  + NREG * NREG;                // 65536 f (B^2)
    float* G1   = C  + NREG * NREG;                // 65536 f (B^3)
    float* G2   = G1 + NREG * NREG;                // 65536 f (B^4)
    float* Einv = G2 + NREG * NREG;                // 256 f
    u16*   Mh   = (u16*)(Einv + NREG);             // 65536 u16 (16B-aligned)
    u16*   Ml   = Mh + NREG * NREG;                // 65536 u16

    k_prep<<<256, 256, 0, stream>>>(kernels, Wlin, Wfeat, B, Einv);
    k_mm  <<<64,  256, 0, stream>>>(B, B, C);
    k_mm2 <<<128, 256, 0, stream>>>(B, C, G1, G2);
    k_comb<<<256, 256, 0, stream>>>(B, C, G1, G2, Einv, Mh, Ml);
    k_main<<<256, 256, 0, stream>>>(inputs, Wfeat, Mh, Ml, out);
}

// Round 9
// 61.643 us; speedup vs baseline: 1.3667x; 1.0141x over previous
//
#include <hip/hip_runtime.h>

// CRF-RNN collapsed: out[t,i] = sum_j M[i,j] * orig[t,j],
//   orig[t,j] = sum_m inputs[t,j,m]*W_feat[m]
//   M = (I + B + B^2 + B^3) * diag(1/denom) + B^4
// Stage-2 via split-bf16 MFMA: x = hi + lo, A*B ~= Ah*Bh + Ah*Bl + Al*Bh.

#define NREG 256   // N
#define KG   16    // gaussian kernels
#define MF   8     // features

typedef unsigned short u16;
typedef __attribute__((ext_vector_type(8))) short short8;   // 8 bf16 = 4 VGPR
typedef __attribute__((ext_vector_type(4))) float f32x4;

__device__ __forceinline__ void async_copy16(const void* g, void* l) {
    __builtin_amdgcn_global_load_lds(
        (const __attribute__((address_space(1))) void*)g,
        (__attribute__((address_space(3))) void*)l,
        16, 0, 0);
}

__device__ __forceinline__ u16 bf16_rne(float x) {
    unsigned u = __float_as_uint(x);
    return (u16)((u + 0x7FFFu + ((u >> 16) & 1u)) >> 16);
}
__device__ __forceinline__ float bf16_to_f(u16 h) {
    return __uint_as_float(((unsigned)h) << 16);
}

// ---------------- K1: Kmat row, denom, B, Einv ----------------
__global__ __launch_bounds__(256) void k_prep(const float* __restrict__ kern,
                                              const float* __restrict__ Wlin,
                                              const float* __restrict__ Wfeat,
                                              float* __restrict__ B,
                                              float* __restrict__ Einv) {
    const int i = blockIdx.x, j = threadIdx.x;
    const float* kp = kern + ((size_t)i * NREG + j) * KG;
    float4 w0 = *(const float4*)(Wlin + 0);
    float4 w1 = *(const float4*)(Wlin + 4);
    float4 w2 = *(const float4*)(Wlin + 8);
    float4 w3 = *(const float4*)(Wlin + 12);
    float4 v0 = *(const float4*)(kp + 0);
    float4 v1 = *(const float4*)(kp + 4);
    float4 v2 = *(const float4*)(kp + 8);
    float4 v3 = *(const float4*)(kp + 12);
    float km = v0.x*w0.x + v0.y*w0.y + v0.z*w0.z + v0.w*w0.w
             + v1.x*w1.x + v1.y*w1.y + v1.z*w1.z + v1.w*w1.w
             + v2.x*w2.x + v2.y*w2.y + v2.z*w2.z + v2.w*w2.w
             + v3.x*w3.x + v3.y*w3.y + v3.z*w3.z + v3.w*w3.w;

    __shared__ float red[256];
    red[j] = km;
    __syncthreads();
    for (int s = 128; s > 0; s >>= 1) {
        if (j < s) red[j] += red[j + s];
        __syncthreads();
    }
    __shared__ float sden;
    if (j == 0) {
        float fw = 0.f;
#pragma unroll
        for (int m = 0; m < MF; ++m) fw += Wfeat[m];
        float den = fw + 2.f * red[0];
        sden = den;
        Einv[i] = 1.f / den;
    }
    __syncthreads();
    B[(size_t)i * NREG + j] = 2.f * km / sden;
}

// ---------------- generic 256x256 matmul body (Out = A*Bm) ----------------
__device__ __forceinline__ void mm_body(const float* __restrict__ A,
                                        const float* __restrict__ Bm,
                                        float* __restrict__ Out,
                                        int i0, int tid) {
    __shared__ float Ar[4][NREG];
#pragma unroll
    for (int r = 0; r < 4; ++r) Ar[r][tid] = A[(size_t)(i0 + r) * NREG + tid];
    __syncthreads();
    float acc0 = 0.f, acc1 = 0.f, acc2 = 0.f, acc3 = 0.f;
    for (int l = 0; l < NREG; l += 4) {
        float b0 = Bm[(size_t)(l + 0) * NREG + tid];
        float b1 = Bm[(size_t)(l + 1) * NREG + tid];
        float b2 = Bm[(size_t)(l + 2) * NREG + tid];
        float b3 = Bm[(size_t)(l + 3) * NREG + tid];
        float4 a0 = *(const float4*)&Ar[0][l];
        float4 a1 = *(const float4*)&Ar[1][l];
        float4 a2 = *(const float4*)&Ar[2][l];
        float4 a3 = *(const float4*)&Ar[3][l];
        acc0 += a0.x*b0 + a0.y*b1 + a0.z*b2 + a0.w*b3;
        acc1 += a1.x*b0 + a1.y*b1 + a1.z*b2 + a1.w*b3;
        acc2 += a2.x*b0 + a2.y*b1 + a2.z*b2 + a2.w*b3;
        acc3 += a3.x*b0 + a3.y*b1 + a3.z*b2 + a3.w*b3;
    }
    Out[(size_t)(i0 + 0) * NREG + tid] = acc0;
    Out[(size_t)(i0 + 1) * NREG + tid] = acc1;
    Out[(size_t)(i0 + 2) * NREG + tid] = acc2;
    Out[(size_t)(i0 + 3) * NREG + tid] = acc3;
}

__global__ __launch_bounds__(256) void k_mm(const float* __restrict__ A,
                                            const float* __restrict__ Bm,
                                            float* __restrict__ Out) {
    mm_body(A, Bm, Out, blockIdx.x * 4, threadIdx.x);
}

__global__ __launch_bounds__(256) void k_mm2(const float* __restrict__ B,
                                             const float* __restrict__ C,
                                             float* __restrict__ G1,
                                             float* __restrict__ G2) {
    const bool second = blockIdx.x >= 64;
    const float* A = second ? C : B;
    float* Out = second ? G2 : G1;
    mm_body(A, C, Out, (blockIdx.x & 63) * 4, threadIdx.x);
}

// K4: M[i][j] (fp32) -> split bf16 Mh/Ml, row-major [i][j]
__global__ __launch_bounds__(256) void k_comb(const float* __restrict__ B,
                                              const float* __restrict__ C,
                                              const float* __restrict__ G1,
                                              const float* __restrict__ G2,
                                              const float* __restrict__ Einv,
                                              u16* __restrict__ Mh,
                                              u16* __restrict__ Ml) {
    const int i = blockIdx.x, j = threadIdx.x;
    const size_t idx = (size_t)i * NREG + j;
    float v = ((i == j) ? 1.f : 0.f) + B[idx] + C[idx] + G1[idx];
    v = v * Einv[j] + G2[idx];
    u16 h = bf16_rne(v);
    float lo = v - bf16_to_f(h);
    Mh[idx] = h;
    Ml[idx] = bf16_rne(lo);
}

// ---------------- K5: fused feature-reduce + MFMA GEMM ----------------
// Block = 512 thr (8 waves = 2/SIMD), 64 t-rows; grid 256 (1 block/CU).
// Stage 1: per-wave 4-deep async ring (2 KB chunks), 8 loads in flight/wave.
// Stage 2: 4 K-panels of 64 j; B panels live in the SAME LDS as the ring
//          (ring dead after stage-1 sync). Split-bf16, 3 MFMA products.
// XOR swizzle (r8-verified): 16B-chunk index ^= (row & 7).
__global__ __launch_bounds__(512, 1) void k_main(const float* __restrict__ in,
                                                 const float* __restrict__ Wfeat,
                                                 const u16* __restrict__ Mh,
                                                 const u16* __restrict__ Ml,
                                                 float* __restrict__ out) {
    __shared__ __align__(16) u16 Ah[64 * 256];       // 32 KB
    __shared__ __align__(16) u16 Al[64 * 256];       // 32 KB
    __shared__ __align__(16) u16 BhBl[2][256 * 64];  // 64 KB: B panels / ring union
    u16* Bh = &BhBl[0][0];
    u16* Bl = &BhBl[1][0];
    float (*raws)[4][512] = (float (*)[4][512])&BhBl[0][0];  // 8w x 4slots x 2KB

    const int tid = threadIdx.x, lane = tid & 63, wid = tid >> 6;  // wid 0..7
    const size_t t0 = (size_t)blockIdx.x * 64;

    // Wfeat live before any async issue (its waitcnt resolves before the ring)
    float4 wa = *(const float4*)(Wfeat);
    float4 wb = *(const float4*)(Wfeat + 4);
    asm volatile("" :: "v"(wa.x), "v"(wa.y), "v"(wa.z), "v"(wa.w),
                       "v"(wb.x), "v"(wb.y), "v"(wb.z), "v"(wb.w));

    // ---- stage 1: wave streams its 8 t-rows as 32 chunks of 2 KB.
    // chunk c: row tl=c>>2, quarter q=c&3; 2 asyncs of 1 KB; slot c&3.
    const float* wbase = in + (t0 + wid * 8) * (NREG * MF);
#pragma unroll
    for (int c = 0; c < 4; ++c) {       // prologue: fill all 4 slots
        const float* src = wbase + (size_t)(c >> 2) * 2048 + (size_t)(c & 3) * 512;
        async_copy16(src + lane * 4,       &raws[wid][c & 3][0]);
        async_copy16(src + 256 + lane * 4, &raws[wid][c & 3][256]);
    }
#pragma unroll
    for (int c = 0; c < 32; ++c) {
        // wait for oldest chunk (2 loads); tail counts shrink to 0
        if (c < 29)      asm volatile("s_waitcnt vmcnt(6)" ::: "memory");
        else if (c == 29) asm volatile("s_waitcnt vmcnt(4)" ::: "memory");
        else if (c == 30) asm volatile("s_waitcnt vmcnt(2)" ::: "memory");
        else              asm volatile("s_waitcnt vmcnt(0)" ::: "memory");
        __builtin_amdgcn_sched_barrier(0);
        const float* rb = &raws[wid][c & 3][lane * 8];
        float4 a0 = *(const float4*)(rb + 0);
        float4 a1 = *(const float4*)(rb + 4);
        // WAR fence (r7-verified): slot reads must RETURN before its refill
        // is issued (ds_read vs VMEM->LDS write are not cross-ordered).
        asm volatile("s_waitcnt lgkmcnt(0)" ::: "memory");
        __builtin_amdgcn_sched_barrier(0);
        if (c + 4 < 32) {
            const int cn = c + 4;
            const float* src = wbase + (size_t)(cn >> 2) * 2048 + (size_t)(cn & 3) * 512;
            async_copy16(src + lane * 4,       &raws[wid][cn & 3][0]);
            async_copy16(src + 256 + lane * 4, &raws[wid][cn & 3][256]);
        }
        float o = a0.x*wa.x + a0.y*wa.y + a0.z*wa.z + a0.w*wa.w
                + a1.x*wb.x + a1.y*wb.y + a1.z*wb.z + a1.w*wb.w;
        u16 h  = bf16_rne(o);
        u16 l2 = bf16_rne(o - bf16_to_f(h));
        const int tl = c >> 2, q = c & 3;
        const int t = wid * 8 + tl;                 // t&7 == tl
        const int chunk = q * 8 + (lane >> 3);      // j>>3 within row
        const int swz = chunk ^ tl;                 // low-3-bit XOR swizzle
        const int idx = t * 256 + swz * 8 + (lane & 7);
        Ah[idx] = h;
        Al[idx] = l2;
    }
    __syncthreads();   // ring fully consumed; A splits resident; vmcnt drained

    // ---- stage 2: 4 K-panels of 64 j. Wave w: m-tile w>>1, n-half w&1.
    const int mrow = (wid >> 1) * 16 + (lane & 15);
    const int nh   = (wid & 1) * 8;
    f32x4 acc[8];
#pragma unroll
    for (int n = 0; n < 8; ++n) acc[n] = (f32x4){0.f, 0.f, 0.f, 0.f};

    for (int p = 0; p < 4; ++p) {
        if (p) __syncthreads();      // previous panel fully consumed
        // stage B panel p: 64 gll of 1 KB (8 i-rows each); 8 per wave.
        // dest linear; source pre-swizzled: src chunk = (lds chunk)^(irow&7)
#pragma unroll
        for (int s = 0; s < 8; ++s) {
            const int g = s * 8 + wid;              // 0..63
            const int i0 = (g & 31) * 8;
            const u16* sg = (g >> 5) ? Ml : Mh;
            u16* dg = (g >> 5) ? Bl : Bh;
            const int irow = i0 + (lane >> 3);
            const int ch = (lane & 7) ^ (lane >> 3);
            async_copy16(sg + (size_t)irow * NREG + p * 64 + ch * 8,
                         dg + i0 * 64);
        }
        __syncthreads();             // drains vmcnt -> panel resident

#pragma unroll
        for (int kst = 0; kst < 2; ++kst) {
            const int achunk = (8 * p + 4 * kst + (lane >> 4)) ^ (lane & 7);
            short8 a_h = *(const short8*)(Ah + mrow * 256 + achunk * 8);
            short8 a_l = *(const short8*)(Al + mrow * 256 + achunk * 8);
#pragma unroll
            for (int n = 0; n < 8; ++n) {
                const int irow = (nh + n) * 16 + (lane & 15);
                const int bchunk = (4 * kst + (lane >> 4)) ^ (lane & 7);
                short8 b_h = *(const short8*)(Bh + irow * 64 + bchunk * 8);
                short8 b_l = *(const short8*)(Bl + irow * 64 + bchunk * 8);
                acc[n] = __builtin_amdgcn_mfma_f32_16x16x32_bf16(a_h, b_h, acc[n], 0, 0, 0);
                acc[n] = __builtin_amdgcn_mfma_f32_16x16x32_bf16(a_h, b_l, acc[n], 0, 0, 0);
                acc[n] = __builtin_amdgcn_mfma_f32_16x16x32_bf16(a_l, b_h, acc[n], 0, 0, 0);
            }
        }
    }

    // ---- epilogue: D col = lane&15 (i), row = (lane>>4)*4 + reg (t)
    const size_t tbase = t0 + (wid >> 1) * 16 + (lane >> 4) * 4;
#pragma unroll
    for (int n = 0; n < 8; ++n) {
#pragma unroll
        for (int r = 0; r < 4; ++r) {
            out[(tbase + r) * NREG + (nh + n) * 16 + (lane & 15)] = acc[n][r];
        }
    }
}

extern "C" void kernel_launch(void* const* d_in, const int* in_sizes, int n_in,
                              void* d_out, int out_size, void* d_ws, size_t ws_size,
                              hipStream_t stream) {
    const float* inputs  = (const float*)d_in[0];  // (16384, 256, 8)
    const float* kernels = (const float*)d_in[1];  // (256, 256, 16)
    const float* Wfeat   = (const float*)d_in[2];  // (1, 8)
    const float* Wlin    = (const float*)d_in[3];  // (1, 16)
    float* out = (float*)d_out;                    // (16384, 256)

    float* ws   = (float*)d_ws;                    // ~1.26 MB
    float* B    = ws;                              // 65536 f
    float* C    = B  + NREG * NREG;                // 65536 f (B^2)
    float* G1   = C  + NREG * NREG;                // 65536 f (B^3)
    float* G2   = G1 + NREG * NREG;                // 65536 f (B^4)
    float* Einv = G2 + NREG * NREG;                // 256 f
    u16*   Mh   = (u16*)(Einv + NREG);             // 65536 u16 (16B-aligned)
    u16*   Ml   = Mh + NREG * NREG;                // 65536 u16

    k_prep<<<256, 256, 0, stream>>>(kernels, Wlin, Wfeat, B, Einv);
    k_mm  <<<64,  256, 0, stream>>>(B, B, C);
    k_mm2 <<<128, 256, 0, stream>>>(B, C, G1, G2);
    k_comb<<<256, 256, 0, stream>>>(B, C, G1, G2, Einv, Mh, Ml);
    k_main<<<256, 512, 0, stream>>>(inputs, Wfeat, Mh, Ml, out);
}